// Round 1
// baseline (298.099 us; speedup 1.0000x reference)
//
#include <hip/hip_runtime.h>

// Problem constants (from reference setup_inputs):
//   burst:   (n=4, d=8, c=3, h=128, w=128)  fp32
//   kernels: (n=4, d=8, r=4, k=5, k=5, h=128, w=128) fp32
//   out:     (n=4, d=8, c=3, 256, 256) fp32  (pixel-shuffle s=2)
#define HH 128
#define WW 128
#define CC 3
#define RR 4
#define KK 5
#define ND 32          // n*d
#define HW (HH*WW)

__global__ __launch_bounds__(256) void adaptive_conv_ps(
    const float* __restrict__ burst,   // (nd, c, h, w)
    const float* __restrict__ kern,    // (nd, r, k, k, h, w)
    float* __restrict__ out)           // (nd, c, 2h, 2w)
{
    int t  = blockIdx.x * blockDim.x + threadIdx.x;
    int w  = t & (WW - 1);
    int h  = (t >> 7) & (HH - 1);
    int nd = t >> 14;            // 0..31

    const float* bptr = burst + (size_t)nd * CC * HW;
    const float* kptr = kern  + (size_t)nd * RR * KK * KK * HW + h * WW + w;

    // Load 3x5x5 burst patch (zero-padded borders). Heavily cache-resident.
    float patch[CC][KK * KK];
#pragma unroll
    for (int c = 0; c < CC; ++c) {
#pragma unroll
        for (int i = 0; i < KK; ++i) {
            int  y  = h + i - 2;
            bool yv = (unsigned)y < (unsigned)HH;
#pragma unroll
            for (int j = 0; j < KK; ++j) {
                int  x = w + j - 2;
                bool v = yv && ((unsigned)x < (unsigned)WW);
                patch[c][i * KK + j] = v ? bptr[c * HW + y * WW + x] : 0.0f;
            }
        }
    }

    float acc[CC][RR];
#pragma unroll
    for (int c = 0; c < CC; ++c)
#pragma unroll
        for (int r = 0; r < RR; ++r)
            acc[c][r] = 0.0f;

    // Stream the 100 per-pixel kernel taps (coalesced along w), FMA into 12 accs.
#pragma unroll
    for (int r = 0; r < RR; ++r) {
#pragma unroll
        for (int ij = 0; ij < KK * KK; ++ij) {
            float kv = kptr[(size_t)(r * KK * KK + ij) * HW];
#pragma unroll
            for (int c = 0; c < CC; ++c)
                acc[c][r] += kv * patch[c][ij];
        }
    }

    // Pixel shuffle write: out[nd, c, 2h+si, 2w+sj] = acc[c][si*2+sj]
#pragma unroll
    for (int c = 0; c < CC; ++c) {
#pragma unroll
        for (int si = 0; si < 2; ++si) {
            float2 v = make_float2(acc[c][si * 2 + 0], acc[c][si * 2 + 1]);
            float* o = out + (((size_t)(nd * CC + c) * (2 * HH) + (2 * h + si)) * (2 * WW)) + 2 * w;
            *(float2*)o = v;
        }
    }
}

extern "C" void kernel_launch(void* const* d_in, const int* in_sizes, int n_in,
                              void* d_out, int out_size, void* d_ws, size_t ws_size,
                              hipStream_t stream) {
    const float* burst = (const float*)d_in[0];
    const float* kern  = (const float*)d_in[1];
    float* out = (float*)d_out;

    const int total = ND * HH * WW;          // 524288 threads, one per (nd,h,w)
    const int block = 256;
    const int grid  = total / block;         // 2048 blocks
    adaptive_conv_ps<<<grid, block, 0, stream>>>(burst, kern, out);
}